// Round 1
// baseline (71.241 us; speedup 1.0000x reference)
//
#include <hip/hip_runtime.h>

#define HH 256
#define WW 256
#define NPIX (HH * WW)   // 65536
#define NB 8
#define NN 64
#define KK 32

__device__ __forceinline__ float rcpf(float x) { return __builtin_amdgcn_rcpf(x); }

// Evaluate one prior's contribution: a = conf * sigmoid(s) * gauss; S1 += a, S2 += a^2
__device__ __forceinline__ void prior_eval(float s, float fx, float fy,
                                           const float4 L, float cf,
                                           float& S1, float& S2) {
    float isx = rcpf(L.z), isy = rcpf(L.w);
    float dx = (fx - L.x) * isx;
    float dy = (fy - L.y) * isy;
    float g  = __expf(-0.5f * fmaf(dx, dx, dy * dy));
    float a  = g * rcpf(1.0f + __expf(-s)) * cf;
    S1 += a;
    S2 = fmaf(a, a, S2);
}

// Phase 1: fc[b, pix] = 1 - S2/(S1+1e-5). One thread = 2 pixels of one batch b.
// b comes from blockIdx only -> masks/loc/conf addresses are wave-uniform (scalarizable).
__global__ __launch_bounds__(256) void k_phase1(
    const float* __restrict__ loc,    // [B,N,4]
    const float* __restrict__ masks,  // [B,N,K]
    const float* __restrict__ proto,  // [B,H,W,K]
    const float* __restrict__ conf,   // [B,N]
    float* __restrict__ fcb)          // [B, NPIX]
{
    const int tiles = NPIX / 512;            // 128 tiles of 512 pixels
    const int b    = blockIdx.x / tiles;     // wave-uniform
    const int tile = blockIdx.x - b * tiles;
    const int tid  = threadIdx.x;
    const int pix0 = tile * 512 + tid;
    const int pix1 = pix0 + 256;

    const float inv = 1.0f / 256.0f;
    const float fx0 = ((pix0 & 255) + 0.5f) * inv;
    const float fy0 = ((pix0 >> 8) + 0.5f) * inv;
    const float fx1 = ((pix1 & 255) + 0.5f) * inv;
    const float fy1 = ((pix1 >> 8) + 0.5f) * inv;

    const float4* p40 = (const float4*)(proto + ((size_t)b * NPIX + pix0) * KK);
    const float4* p41 = (const float4*)(proto + ((size_t)b * NPIX + pix1) * KK);
    float4 A0[8], A1[8];
#pragma unroll
    for (int j = 0; j < 8; ++j) A0[j] = p40[j];
#pragma unroll
    for (int j = 0; j < 8; ++j) A1[j] = p41[j];

    const float4* m4 = (const float4*)(masks + (size_t)b * NN * KK);
    const float4* l4 = (const float4*)(loc + (size_t)b * NN * 4);
    const float*  cf = conf + b * NN;

    float S10 = 0.f, S20 = 0.f, S11 = 0.f, S21 = 0.f;
    for (int n = 0; n < NN; ++n) {
        float sa0 = 0.f, sb0 = 0.f, sa1 = 0.f, sb1 = 0.f;  // 4 indep FMA chains
#pragma unroll
        for (int j = 0; j < 8; j += 2) {
            float4 m = m4[n * 8 + j];
            sa0 = fmaf(A0[j].w, m.w, fmaf(A0[j].z, m.z, fmaf(A0[j].y, m.y, fmaf(A0[j].x, m.x, sa0))));
            sa1 = fmaf(A1[j].w, m.w, fmaf(A1[j].z, m.z, fmaf(A1[j].y, m.y, fmaf(A1[j].x, m.x, sa1))));
            float4 q = m4[n * 8 + j + 1];
            sb0 = fmaf(A0[j+1].w, q.w, fmaf(A0[j+1].z, q.z, fmaf(A0[j+1].y, q.y, fmaf(A0[j+1].x, q.x, sb0))));
            sb1 = fmaf(A1[j+1].w, q.w, fmaf(A1[j+1].z, q.z, fmaf(A1[j+1].y, q.y, fmaf(A1[j+1].x, q.x, sb1))));
        }
        const float4 L = l4[n];
        const float  c = cf[n];
        prior_eval(sa0 + sb0, fx0, fy0, L, c, S10, S20);
        prior_eval(sa1 + sb1, fx1, fy1, L, c, S11, S21);
    }
    fcb[(size_t)b * NPIX + pix0] = 1.0f - S20 * rcpf(S10 + 1e-5f);
    fcb[(size_t)b * NPIX + pix1] = 1.0f - S21 * rcpf(S11 + 1e-5f);
}

// Phase 2: weighted-variance sum over everything -> scalar (atomicAdd per block).
__global__ __launch_bounds__(256) void k_phase2(
    const float* __restrict__ original,  // [B,3,H,W]
    const float* __restrict__ fcb,       // [B, NPIX]
    float* __restrict__ out)
{
    const int pix = blockIdx.x * 256 + threadIdx.x;
    float f[NB];
    float tot = 0.f;
#pragma unroll
    for (int b = 0; b < NB; ++b) { f[b] = fcb[(size_t)b * NPIX + pix]; tot += f[b]; }
    float part = 0.f;
#pragma unroll
    for (int c = 0; c < 3; ++c) {
        float o[NB];
        float wm = 0.f;
#pragma unroll
        for (int b = 0; b < NB; ++b) {
            o[b] = original[((size_t)(b * 3 + c)) * NPIX + pix];
            wm = fmaf(o[b], f[b], wm);
        }
#pragma unroll
        for (int b = 0; b < NB; ++b) {
            float d = o[b] - wm;
            part = fmaf(d * d, f[b], part);
        }
    }
    part *= rcpf(tot);

#pragma unroll
    for (int off = 32; off > 0; off >>= 1) part += __shfl_down(part, off);
    __shared__ float sred[4];
    if ((threadIdx.x & 63) == 0) sred[threadIdx.x >> 6] = part;
    __syncthreads();
    if (threadIdx.x == 0) atomicAdd(out, sred[0] + sred[1] + sred[2] + sred[3]);
}

// Fallback: fully fused, no workspace needed (used only if ws_size too small).
__global__ __launch_bounds__(256) void k_fused(
    const float* __restrict__ original, const float* __restrict__ loc,
    const float* __restrict__ masks, const float* __restrict__ proto,
    const float* __restrict__ conf, float* __restrict__ out)
{
    const int pix = blockIdx.x * 256 + threadIdx.x;
    const float inv = 1.0f / 256.0f;
    const float fx = ((pix & 255) + 0.5f) * inv;
    const float fy = ((pix >> 8) + 0.5f) * inv;

    float f[NB];
    for (int b = 0; b < NB; ++b) {
        const float4* p4 = (const float4*)(proto + ((size_t)b * NPIX + pix) * KK);
        float4 A[8];
#pragma unroll
        for (int j = 0; j < 8; ++j) A[j] = p4[j];
        const float4* m4 = (const float4*)(masks + (size_t)b * NN * KK);
        const float4* l4 = (const float4*)(loc + (size_t)b * NN * 4);
        const float*  cf = conf + b * NN;
        float S1 = 0.f, S2 = 0.f;
        for (int n = 0; n < NN; ++n) {
            float sa = 0.f, sb = 0.f;
#pragma unroll
            for (int j = 0; j < 8; j += 2) {
                float4 m = m4[n * 8 + j];
                sa = fmaf(A[j].w, m.w, fmaf(A[j].z, m.z, fmaf(A[j].y, m.y, fmaf(A[j].x, m.x, sa))));
                float4 q = m4[n * 8 + j + 1];
                sb = fmaf(A[j+1].w, q.w, fmaf(A[j+1].z, q.z, fmaf(A[j+1].y, q.y, fmaf(A[j+1].x, q.x, sb))));
            }
            prior_eval(sa + sb, fx, fy, l4[n], cf[n], S1, S2);
        }
        f[b] = 1.0f - S2 * rcpf(S1 + 1e-5f);
    }
    float tot = 0.f;
#pragma unroll
    for (int b = 0; b < NB; ++b) tot += f[b];
    float part = 0.f;
#pragma unroll
    for (int c = 0; c < 3; ++c) {
        float o[NB];
        float wm = 0.f;
#pragma unroll
        for (int b = 0; b < NB; ++b) {
            o[b] = original[((size_t)(b * 3 + c)) * NPIX + pix];
            wm = fmaf(o[b], f[b], wm);
        }
#pragma unroll
        for (int b = 0; b < NB; ++b) {
            float d = o[b] - wm;
            part = fmaf(d * d, f[b], part);
        }
    }
    part *= rcpf(tot);

#pragma unroll
    for (int off = 32; off > 0; off >>= 1) part += __shfl_down(part, off);
    __shared__ float sred[4];
    if ((threadIdx.x & 63) == 0) sred[threadIdx.x >> 6] = part;
    __syncthreads();
    if (threadIdx.x == 0) atomicAdd(out, sred[0] + sred[1] + sred[2] + sred[3]);
}

extern "C" void kernel_launch(void* const* d_in, const int* in_sizes, int n_in,
                              void* d_out, int out_size, void* d_ws, size_t ws_size,
                              hipStream_t stream) {
    const float* original = (const float*)d_in[0];
    const float* loc      = (const float*)d_in[1];
    const float* masks    = (const float*)d_in[2];
    const float* proto    = (const float*)d_in[3];
    const float* conf     = (const float*)d_in[4];
    float* out = (float*)d_out;

    hipMemsetAsync(out, 0, sizeof(float), stream);

    const size_t fc_bytes = (size_t)NB * NPIX * sizeof(float);
    if (ws_size >= fc_bytes) {
        float* fcb = (float*)d_ws;
        k_phase1<<<NB * (NPIX / 512), 256, 0, stream>>>(loc, masks, proto, conf, fcb);
        k_phase2<<<NPIX / 256, 256, 0, stream>>>(original, fcb, out);
    } else {
        k_fused<<<NPIX / 256, 256, 0, stream>>>(original, loc, masks, proto, conf, out);
    }
}